// Round 10
// baseline (166.150 us; speedup 1.0000x reference)
//
#include <hip/hip_runtime.h>
#include <cstdint>

// Problem constants
#define BATCH 2
#define TT    4
#define CKD   64      // key channels
#define CVD   256     // value channels
#define NQ    2048    // H*W (queries per batch)
#define MM    8192    // T*H*W (memory positions per batch)
#define TQ    32      // queries per block (R10: 64->32, grid 512->1024, 4 blocks/CU)
#define TM    32      // memory rows per inner iteration
#define MSPLIT 8
#define MCHUNK (MM / MSPLIT)   // 1024 = half a T-slice
#define NIT    (MCHUNK / TM)   // 32

typedef unsigned short u16;
typedef __bf16 bf16x8 __attribute__((ext_vector_type(8)));
typedef float  f32x4  __attribute__((ext_vector_type(4)));

struct __attribute__((aligned(8)))  U16x4 { u16 x, y, z, w; };
struct __attribute__((aligned(16))) U16x8 { u16 v[8]; };

__device__ __forceinline__ u16 f2bf(float x) {
    uint32_t u = __float_as_uint(x);
    uint32_t r = (u + 0x7FFFu + ((u >> 16) & 1u)) >> 16;   // RNE
    return (u16)r;
}
__device__ __forceinline__ float bf2f(u16 h) {
    return __uint_as_float(((uint32_t)h) << 16);
}

#define MFMA(a, b, c) __builtin_amdgcn_mfma_f32_16x16x32_bf16((a), (b), (c), 0, 0, 0)

// Workspace layout (bytes)
#define WS_VB   0u           // 8 MB   bf16 V   [bt][c][m]
#define WS_KHI  8388608u     // 2 MB   bf16 Khi [bt][m][c]
#define WS_KLO  10485760u    // 2 MB   bf16 Klo [bt][m][c]
#define WS_QHI  12582912u    // 512 KB bf16 Qhi [b][n][c]
#define WS_QLO  13107200u    // 512 KB
#define WS_LP   13631488u    // 64 KB  fp32 Lp[ms][b][n] (plain stores, msub-combined)
#define WS_UP   13893632u    // 32 MB  fp32 Up[ms][b][n][c] (plain stores)

// ---------------------------------------------------------------------------
// prep_fused: block-range switch:
//   [0,4096)    pool_qv: 2x2 avg-pool query_value -> out channels [0,256)
//   [4096,6144) prep_v : fp32 V -> bf16, same [bt][c][m] layout
//   [6144,6400) prep_kq(mk): coalesced read + LDS transpose -> bf16 hi/lo [m][c]
//   [6400,6464) prep_kq(qk): same for query_key_low
// ---------------------------------------------------------------------------
__global__ __launch_bounds__(256)
void prep_fused(const float* __restrict__ qv, const float* __restrict__ mk,
                const float* __restrict__ qk, const float* __restrict__ mv,
                float* __restrict__ out, u16* __restrict__ vb,
                u16* __restrict__ khi, u16* __restrict__ klo,
                u16* __restrict__ qhi, u16* __restrict__ qlo) {
    __shared__ float tile[64 * 65];   // kq branch only (block-uniform branches)
    const int bid = blockIdx.x;
    const int tid = threadIdx.x;

    if (bid < 4096) {
        // ---- pool_qv ----
        int idx = bid * 256 + tid;
        int n  = idx & 2047;
        int bc = idx >> 11;
        int x = n & 63, y = n >> 6;
        const float* ib = qv + (size_t)bc * (64 * 128) + (2 * y) * 128 + 2 * x;
        float2 r0 = *(const float2*)ib;
        float2 r1 = *(const float2*)(ib + 128);
        int b = bc >> 8, c = bc & 255;
        out[((size_t)(b * 512 + c)) * NQ + n] = 0.25f * (r0.x + r0.y + r1.x + r1.y);
    } else if (bid < 6144) {
        // ---- prep_v ----
        int idx = (bid - 4096) * 256 + tid;        // 0 .. 524287
        const float4* s = (const float4*)mv + (size_t)idx * 2;
        float4 a = s[0], b = s[1];
        U16x8 o;
        o.v[0] = f2bf(a.x); o.v[1] = f2bf(a.y); o.v[2] = f2bf(a.z); o.v[3] = f2bf(a.w);
        o.v[4] = f2bf(b.x); o.v[5] = f2bf(b.y); o.v[6] = f2bf(b.z); o.v[7] = f2bf(b.w);
        *(U16x8*)(vb + (size_t)idx * 8) = o;
    } else {
        // ---- prep_kq: per block one 64c x 64m tile, transposed via LDS ----
        const float* src;
        u16 *dhi, *dlo;
        int blk;
        if (bid < 6400) { src = mk; dhi = khi; dlo = klo; blk = bid - 6144; }
        else            { src = qk; dhi = qhi; dlo = qlo; blk = bid - 6400; }
        const int g  = blk >> 5;           // mk: 0..7, qk: 0..1
        const int mg = blk & 31;           // 64-m tile index
        const float* s = src + (size_t)g * 64 * 2048 + mg * 64;

        // coalesced read: c = tid>>2, q = tid&3; 4 float4 per thread
        const int c = tid >> 2;
        const int q = tid & 3;
        #pragma unroll
        for (int i = 0; i < 4; ++i) {
            float4 v = *(const float4*)(s + (size_t)c * 2048 + q * 16 + i * 4);
            int m = q * 16 + i * 4;
            tile[(m + 0) * 65 + c] = v.x;
            tile[(m + 1) * 65 + c] = v.y;
            tile[(m + 2) * 65 + c] = v.z;
            tile[(m + 3) * 65 + c] = v.w;
        }
        __syncthreads();

        // coalesced write: mo = tid>>2, cb = (tid&3)*16; hi/lo split here
        const int mo = tid >> 2;
        const int cb = (tid & 3) * 16;
        U16x8 h0, h1, l0, l1;
        #pragma unroll
        for (int j = 0; j < 8; ++j) {
            float v = tile[mo * 65 + cb + j];
            u16 h = f2bf(v);
            h0.v[j] = h; l0.v[j] = f2bf(v - bf2f(h));
            float v2 = tile[mo * 65 + cb + 8 + j];
            u16 h2 = f2bf(v2);
            h1.v[j] = h2; l1.v[j] = f2bf(v2 - bf2f(h2));
        }
        size_t o = ((size_t)g * 2048 + mg * 64 + mo) * 64 + cb;
        *(U16x8*)(dhi + o) = h0; *(U16x8*)(dhi + o + 8) = h1;
        *(U16x8*)(dlo + o) = l0; *(U16x8*)(dlo + o + 8) = l1;
    }
}

// ---------------------------------------------------------------------------
// flash_attn (R10): R8 structure (best: 48 us) with TQ=32 and grid 1024
// -> 4 blocks/CU = 16 waves/CU. Work/wave halves; barrier convoys and
// LDS->MFMA latency chains now overlap across 4 resident blocks (m114
// mechanism) instead of stalling 2 lonely waves/SIMD.
// V never staged in LDS (fragment layout == global [c][m], L2 absorbs).
// Per buffer: Khi[32][72] | Klo[32][72] | Ps[32][40]; x2 = 23552 B.
//   stage K(p) | sync1 | QK -> exp -> Ps(p) | sync2 | prefetch | PV
// Grid: 1024 = b(2) x ntile(64) x mchunk(8); mchunk in low bits -> per-XCD
// L2 caches one (bt, m-slice) of K/V. Block 256 = 4 waves.
// QK roles: msub = w&1, nsub = w>>1 (S[msub*16..+16][nsub*16..+16]).
// PV roles: c-quarter = w, all 32 n.
// ---------------------------------------------------------------------------
__global__ __launch_bounds__(256, 4)
void flash_attn(const u16* __restrict__ khi_g, const u16* __restrict__ klo_g,
                const u16* __restrict__ vb_g, const u16* __restrict__ qhi_g,
                const u16* __restrict__ qlo_g, float* __restrict__ Up,
                float* __restrict__ Lp) {
    __shared__ __align__(16) u16 smem[2][5888];   // Khi 2304 | Klo 2304 | Ps 1280

    const int tid    = threadIdx.x;
    const int bx     = blockIdx.x;
    const int mchunk = bx & 7;
    const int ntile  = (bx >> 3) & 63;
    const int b      = bx >> 9;

    const int lane = tid & 63;
    const int w    = tid >> 6;
    const int quad = lane >> 4;
    const int l15  = lane & 15;

    const int bt      = b * TT + (mchunk >> 1);
    const int hw_base = (mchunk & 1) * MCHUNK;

    const int msub = w & 1;             // QK role
    const int nsub = w >> 1;            // QK role

    // ---- Q fragments (this wave's n-16 slice) from pre-transposed global ----
    bf16x8 qh[2], ql[2];                // [kstep]
    {
        size_t o = ((size_t)(b * NQ + ntile * TQ + nsub * 16 + l15)) * 64 + quad * 8;
        qh[0] = *(const bf16x8*)&qhi_g[o];
        qh[1] = *(const bf16x8*)&qhi_g[o + 32];
        ql[0] = *(const bf16x8*)&qlo_g[o];
        ql[1] = *(const bf16x8*)&qlo_g[o + 32];
    }

    const u16* kh_base = khi_g + ((size_t)bt * 2048 + hw_base) * 64;
    const u16* kl_base = klo_g + ((size_t)bt * 2048 + hw_base) * 64;
    // V fragment base for this wave's c-quarter: c = w*64 + cs*16 + l15
    const u16* v_frag_base = vb_g + (size_t)bt * CVD * 2048 + hw_base
                           + (size_t)(w * 64 + l15) * 2048 + quad * 8;

    f32x4 O[2][4];                      // [nsub2][cs4]
    #pragma unroll
    for (int i = 0; i < 2; ++i)
        #pragma unroll
        for (int j = 0; j < 4; ++j)
            O[i][j] = (f32x4){0.f, 0.f, 0.f, 0.f};
    float Lloc = 0.f;                   // per-lane n = nsub*16+l15, partial over this msub

    // K staging lane map
    const int km = tid >> 3;            // 0..31
    const int kc = (tid & 7) * 8;       // 0..56

    // ---- prologue: prefetch iter 0 (K staging regs + V fragment regs) ----
    bf16x8 kh_r = *(const bf16x8*)&kh_base[(size_t)km * 64 + kc];
    bf16x8 kl_r = *(const bf16x8*)&kl_base[(size_t)km * 64 + kc];
    bf16x8 v_cur[4], v_next[4];
    #pragma unroll
    for (int cs = 0; cs < 4; ++cs)
        v_cur[cs] = *(const bf16x8*)&v_frag_base[(size_t)(cs * 16) * 2048];

    #pragma unroll 2
    for (int it = 0; it < NIT; ++it) {
        u16* Khi = smem[it & 1];
        u16* Klo = Khi + 2304;
        u16* Ps  = Khi + 4608;          // [32][40]

        // ---- stage K tile into this iteration's buffer ----
        *(bf16x8*)&Khi[km * 72 + kc] = kh_r;
        *(bf16x8*)&Klo[km * 72 + kc] = kl_r;
        __syncthreads();   // sync1: K staging visible

        // ---- QK: S[msub*16..+16][nsub*16..+16], 3-term hi/lo split ----
        f32x4 acc = (f32x4){0.f, 0.f, 0.f, 0.f};
        #pragma unroll
        for (int ks = 0; ks < 2; ++ks) {
            bf16x8 ah = *(const bf16x8*)&Khi[(msub * 16 + l15) * 72 + ks * 32 + quad * 8];
            bf16x8 al = *(const bf16x8*)&Klo[(msub * 16 + l15) * 72 + ks * 32 + quad * 8];
            acc = MFMA(ah, qh[ks], acc);
            acc = MFMA(ah, ql[ks], acc);
            acc = MFMA(al, qh[ks], acc);
        }
        // ---- P = exp(S) -> Ps[n][m] (A-operand layout); accumulate L ----
        {
            float p0 = __expf(acc[0]);
            float p1 = __expf(acc[1]);
            float p2 = __expf(acc[2]);
            float p3 = __expf(acc[3]);
            Lloc += (p0 + p1) + (p2 + p3);
            U16x4 pk = {f2bf(p0), f2bf(p1), f2bf(p2), f2bf(p3)};
            *(U16x4*)&Ps[(nsub * 16 + l15) * 40 + msub * 16 + quad * 4] = pk;
        }
        __syncthreads();   // sync2: Ps visible; K reads done

        // ---- prefetch it+1 (drains at sync1(it+1), covered by PV span) ----
        if (it + 1 < NIT) {
            const int hw1 = (it + 1) * TM;
            kh_r = *(const bf16x8*)&kh_base[(size_t)(hw1 + km) * 64 + kc];
            kl_r = *(const bf16x8*)&kl_base[(size_t)(hw1 + km) * 64 + kc];
            #pragma unroll
            for (int cs = 0; cs < 4; ++cs)
                v_next[cs] = *(const bf16x8*)&v_frag_base[(size_t)(cs * 16) * 2048 + hw1];
        }

        // ---- PV: wave owns O[32 n][c-quarter w*64..+64], K=32 (one step) ----
        bf16x8 a2[2];
        #pragma unroll
        for (int ns = 0; ns < 2; ++ns)
            a2[ns] = *(const bf16x8*)&Ps[(ns * 16 + l15) * 40 + quad * 8];
        #pragma unroll
        for (int cs = 0; cs < 4; ++cs)
            #pragma unroll
            for (int ns = 0; ns < 2; ++ns)
                O[ns][cs] = MFMA(a2[ns], v_cur[cs], O[ns][cs]);

        // ---- rotate V prefetch ----
        #pragma unroll
        for (int cs = 0; cs < 4; ++cs)
            v_cur[cs] = v_next[cs];
        // no barrier: next staging writes the other buffer
    }

    // ---- L: fold quads, combine the two msub waves via LDS, store ----
    // smem buffer 0 is dead after sync1(it=31) barrier -> safe as scratch.
    float* Larr = (float*)smem[0];      // [2 msub][32 n]
    {
        float v = Lloc;
        v += __shfl_xor(v, 16);
        v += __shfl_xor(v, 32);
        if (quad == 0)
            Larr[msub * 32 + nsub * 16 + l15] = v;
    }
    __syncthreads();
    if (tid < 32)
        Lp[((size_t)mchunk * BATCH + b) * NQ + ntile * TQ + tid] = Larr[tid] + Larr[32 + tid];

    // ---- U partials: plain coalesced fp32 stores, layout [ms][b][n][c] ----
    float* ubase = Up + (((size_t)mchunk * BATCH + b) * NQ + ntile * TQ) * CVD + w * 64;
    #pragma unroll
    for (int ns = 0; ns < 2; ++ns) {
        #pragma unroll
        for (int cs = 0; cs < 4; ++cs) {
            #pragma unroll
            for (int r = 0; r < 4; ++r) {
                int n_local = ns * 16 + quad * 4 + r;
                ubase[(size_t)n_local * CVD + cs * 16 + l15] = O[ns][cs][r];
            }
        }
    }
}

// ---------------------------------------------------------------------------
// reduce_div: out[b,256+c,n] = (sum_ms Up[ms][b][n][c]) / (sum_ms Lp[ms][b][n])
// Grid: 1024 = b(2) x nslab(128, 16 n each) x cquarter(4, 64 c each).
// ---------------------------------------------------------------------------
__global__ __launch_bounds__(256) void reduce_div(const float* __restrict__ Up,
                                                  const float* __restrict__ Lp,
                                                  float* __restrict__ out) {
    __shared__ float lds[16 * 65];
    const int tid = threadIdx.x;
    const int cq  = blockIdx.x & 3;
    const int n0  = ((blockIdx.x >> 2) & 127) * 16;
    const int b   = blockIdx.x >> 9;

    const int n_local = tid >> 4;          // 0..15
    const int c_loc   = (tid & 15) * 4;    // 0..60
    const int c       = cq * 64 + c_loc;

    float4 acc = {0.f, 0.f, 0.f, 0.f};
    for (int ms = 0; ms < MSPLIT; ++ms) {
        float4 v = *(const float4*)(Up + (((size_t)ms * BATCH + b) * NQ + n0 + n_local) * CVD + c);
        acc.x += v.x; acc.y += v.y; acc.z += v.z; acc.w += v.w;
    }

    float Lsum = 0.f;
    #pragma unroll
    for (int ms = 0; ms < MSPLIT; ++ms)
        Lsum += Lp[((size_t)ms * BATCH + b) * NQ + n0 + n_local];
    const float inv = 1.0f / Lsum;

    lds[n_local * 65 + c_loc + 0] = acc.x * inv;
    lds[n_local * 65 + c_loc + 1] = acc.y * inv;
    lds[n_local * 65 + c_loc + 2] = acc.z * inv;
    lds[n_local * 65 + c_loc + 3] = acc.w * inv;
    __syncthreads();

    // transpose write: out[b][256+cq*64+c_out][n0 + nq .. +4)
    const int c_out = tid >> 2;            // 0..63
    const int nq    = (tid & 3) * 4;       // 0..12
    float4 v;
    v.x = lds[(nq + 0) * 65 + c_out];
    v.y = lds[(nq + 1) * 65 + c_out];
    v.z = lds[(nq + 2) * 65 + c_out];
    v.w = lds[(nq + 3) * 65 + c_out];
    *(float4*)(out + ((size_t)(b * 512 + 256 + cq * 64 + c_out)) * NQ + n0 + nq) = v;
}

extern "C" void kernel_launch(void* const* d_in, const int* in_sizes, int n_in,
                              void* d_out, int out_size, void* d_ws, size_t ws_size,
                              hipStream_t stream) {
    const float* qv = (const float*)d_in[0];   // query_value       [2,256,64,128]
    const float* mk = (const float*)d_in[1];   // memory_keys_low   [2,4,64,32,64]
    const float* mv = (const float*)d_in[2];   // memory_values_low [2,4,256,32,64]
    const float* qk = (const float*)d_in[3];   // query_key_low     [2,64,32,64]
    float* out = (float*)d_out;                // [2,512,32,64] fp32

    u16*   vb  = (u16*)((char*)d_ws + WS_VB);
    u16*   khi = (u16*)((char*)d_ws + WS_KHI);
    u16*   klo = (u16*)((char*)d_ws + WS_KLO);
    u16*   qhi = (u16*)((char*)d_ws + WS_QHI);
    u16*   qlo = (u16*)((char*)d_ws + WS_QLO);
    float* Lp  = (float*)((char*)d_ws + WS_LP);
    float* Up  = (float*)((char*)d_ws + WS_UP);

    prep_fused<<<6464, 256, 0, stream>>>(qv, mk, qk, mv, out, vb, khi, klo, qhi, qlo);
    flash_attn<<<1024, 256, 0, stream>>>(khi, klo, vb, qhi, qlo, Up, Lp);
    reduce_div<<<1024, 256, 0, stream>>>(Up, Lp, out);
}

// Round 11
// 159.402 us; speedup vs baseline: 1.0423x; 1.0423x over previous
//
#include <hip/hip_runtime.h>
#include <cstdint>

// Problem constants
#define BATCH 2
#define TT    4
#define CKD   64      // key channels
#define CVD   256     // value channels
#define NQ    2048    // H*W (queries per batch)
#define MM    8192    // T*H*W (memory positions per batch)
#define TQ    64      // queries per block
#define TM    32      // memory rows per inner iteration
#define MSPLIT 8
#define MCHUNK (MM / MSPLIT)   // 1024 = half a T-slice
#define NIT    (MCHUNK / TM)   // 32

typedef unsigned short u16;
typedef __bf16 bf16x8 __attribute__((ext_vector_type(8)));
typedef float  f32x4  __attribute__((ext_vector_type(4)));

struct __attribute__((aligned(8)))  U16x4 { u16 x, y, z, w; };
struct __attribute__((aligned(16))) U16x8 { u16 v[8]; };

__device__ __forceinline__ u16 f2bf(float x) {
    uint32_t u = __float_as_uint(x);
    uint32_t r = (u + 0x7FFFu + ((u >> 16) & 1u)) >> 16;   // RNE
    return (u16)r;
}
__device__ __forceinline__ float bf2f(u16 h) {
    return __uint_as_float(((uint32_t)h) << 16);
}

#define MFMA(a, b, c) __builtin_amdgcn_mfma_f32_16x16x32_bf16((a), (b), (c), 0, 0, 0)

// Workspace layout (bytes)
#define WS_VB   0u           // 8 MB   bf16 V   [bt][c][m]
#define WS_KHI  8388608u     // 2 MB   bf16 Khi [bt][m][c]
#define WS_KLO  10485760u    // 2 MB   bf16 Klo [bt][m][c]
#define WS_QHI  12582912u    // 512 KB bf16 Qhi [b][n][c]  (pre-scaled by log2(e))
#define WS_QLO  13107200u    // 512 KB
#define WS_LP   13631488u    // 256 KB fp32 Lp[ms][msub][b][n] (plain stores)
#define WS_UP   13893632u    // 32 MB  fp32 Up[ms][b][n][c]   (plain stores)

// ---------------------------------------------------------------------------
// prep_fused: block-range switch:
//   [0,4096)    pool_qv: 2x2 avg-pool query_value -> out channels [0,256)
//   [4096,6144) prep_v : fp32 V -> bf16, same [bt][c][m] layout
//   [6144,6400) prep_kq(mk): coalesced read + LDS transpose -> bf16 hi/lo [m][c]
//   [6400,6464) prep_kq(qk): same, but values pre-scaled by log2(e) so the
//               flash kernel can use exp2f (raw v_exp_f32, no mul)
// ---------------------------------------------------------------------------
__global__ __launch_bounds__(256)
void prep_fused(const float* __restrict__ qv, const float* __restrict__ mk,
                const float* __restrict__ qk, const float* __restrict__ mv,
                float* __restrict__ out, u16* __restrict__ vb,
                u16* __restrict__ khi, u16* __restrict__ klo,
                u16* __restrict__ qhi, u16* __restrict__ qlo) {
    __shared__ float tile[64 * 65];   // kq branch only (block-uniform branches)
    const int bid = blockIdx.x;
    const int tid = threadIdx.x;

    if (bid < 4096) {
        // ---- pool_qv ----
        int idx = bid * 256 + tid;
        int n  = idx & 2047;
        int bc = idx >> 11;
        int x = n & 63, y = n >> 6;
        const float* ib = qv + (size_t)bc * (64 * 128) + (2 * y) * 128 + 2 * x;
        float2 r0 = *(const float2*)ib;
        float2 r1 = *(const float2*)(ib + 128);
        int b = bc >> 8, c = bc & 255;
        out[((size_t)(b * 512 + c)) * NQ + n] = 0.25f * (r0.x + r0.y + r1.x + r1.y);
    } else if (bid < 6144) {
        // ---- prep_v ----
        int idx = (bid - 4096) * 256 + tid;        // 0 .. 524287
        const float4* s = (const float4*)mv + (size_t)idx * 2;
        float4 a = s[0], b = s[1];
        U16x8 o;
        o.v[0] = f2bf(a.x); o.v[1] = f2bf(a.y); o.v[2] = f2bf(a.z); o.v[3] = f2bf(a.w);
        o.v[4] = f2bf(b.x); o.v[5] = f2bf(b.y); o.v[6] = f2bf(b.z); o.v[7] = f2bf(b.w);
        *(U16x8*)(vb + (size_t)idx * 8) = o;
    } else {
        // ---- prep_kq: per block one 64c x 64m tile, transposed via LDS ----
        const float* src;
        u16 *dhi, *dlo;
        int blk;
        float scale;
        if (bid < 6400) { src = mk; dhi = khi; dlo = klo; blk = bid - 6144; scale = 1.0f; }
        else            { src = qk; dhi = qhi; dlo = qlo; blk = bid - 6400;
                          scale = 1.4426950408889634f; }   // log2(e) into Q only
        const int g  = blk >> 5;           // mk: 0..7, qk: 0..1
        const int mg = blk & 31;           // 64-m tile index
        const float* s = src + (size_t)g * 64 * 2048 + mg * 64;

        // coalesced read: c = tid>>2, q = tid&3; 4 float4 per thread
        const int c = tid >> 2;
        const int q = tid & 3;
        #pragma unroll
        for (int i = 0; i < 4; ++i) {
            float4 v = *(const float4*)(s + (size_t)c * 2048 + q * 16 + i * 4);
            int m = q * 16 + i * 4;
            tile[(m + 0) * 65 + c] = v.x;
            tile[(m + 1) * 65 + c] = v.y;
            tile[(m + 2) * 65 + c] = v.z;
            tile[(m + 3) * 65 + c] = v.w;
        }
        __syncthreads();

        // coalesced write: mo = tid>>2, cb = (tid&3)*16; scale + hi/lo split
        const int mo = tid >> 2;
        const int cb = (tid & 3) * 16;
        U16x8 h0, h1, l0, l1;
        #pragma unroll
        for (int j = 0; j < 8; ++j) {
            float v = tile[mo * 65 + cb + j] * scale;
            u16 h = f2bf(v);
            h0.v[j] = h; l0.v[j] = f2bf(v - bf2f(h));
            float v2 = tile[mo * 65 + cb + 8 + j] * scale;
            u16 h2 = f2bf(v2);
            h1.v[j] = h2; l1.v[j] = f2bf(v2 - bf2f(h2));
        }
        size_t o = ((size_t)g * 2048 + mg * 64 + mo) * 64 + cb;
        *(U16x8*)(dhi + o) = h0; *(U16x8*)(dhi + o + 8) = h1;
        *(U16x8*)(dlo + o) = l0; *(U16x8*)(dlo + o + 8) = l1;
    }
}

// ---------------------------------------------------------------------------
// flash_attn (R11): NEITHER K nor V staged in LDS. QK A-fragments
// (K[m=msub*16+l15][c=quad*8..]) load straight from the pre-transposed [m][c]
// global layout (same proven trick as R8's V). Only P crosses waves -> ONE
// barrier per iteration, Ps double-buffered (WAR separated by the barrier).
// Prefetch for it+1 issues at the TOP of the iter, so the vmcnt(0) drain at
// the barrier is covered by the whole QK+exp span.
//   [prefetch K',V'] QK(K regs) -> exp2 -> Ps(p) | SYNC | PV(Ps p, V regs)
// QK: 4 independent MFMA chains (hi 2-deep, lo 4-deep) instead of 2x6.
// Grid: 512 = b(2) x ntile(32) x mchunk(8). Block 256 = 4 waves.
// QK roles: msub = w&1, nsubpair = w>>1. PV roles: c-quarter = w, all 64 n.
// ---------------------------------------------------------------------------
__global__ __launch_bounds__(256, 2)
void flash_attn(const u16* __restrict__ khi_g, const u16* __restrict__ klo_g,
                const u16* __restrict__ vb_g, const u16* __restrict__ qhi_g,
                const u16* __restrict__ qlo_g, float* __restrict__ Up,
                float* __restrict__ Lp) {
    __shared__ __align__(16) u16 Ps2[2][2560];   // [64][40] per buffer (80 B pitch)

    const int tid    = threadIdx.x;
    const int bx     = blockIdx.x;
    const int mchunk = bx & 7;
    const int ntile  = (bx >> 3) & 31;
    const int b      = bx >> 8;

    const int lane = tid & 63;
    const int w    = tid >> 6;
    const int quad = lane >> 4;
    const int l15  = lane & 15;

    const int bt      = b * TT + (mchunk >> 1);
    const int hw_base = (mchunk & 1) * MCHUNK;

    const int msub     = w & 1;         // QK role
    const int nsubpair = w >> 1;        // QK role

    // ---- Q fragments (pre-scaled by log2 e) from pre-transposed global ----
    bf16x8 qh[2][2], ql[2][2];          // [nsi][kstep]
    {
        const int nbase = ntile * TQ + nsubpair * 32;
        #pragma unroll
        for (int nsi = 0; nsi < 2; ++nsi) {
            size_t o = ((size_t)(b * NQ + nbase + nsi * 16 + l15)) * 64 + quad * 8;
            qh[nsi][0] = *(const bf16x8*)&qhi_g[o];
            qh[nsi][1] = *(const bf16x8*)&qhi_g[o + 32];
            ql[nsi][0] = *(const bf16x8*)&qlo_g[o];
            ql[nsi][1] = *(const bf16x8*)&qlo_g[o + 32];
        }
    }

    const u16* kh_base = khi_g + ((size_t)bt * 2048 + hw_base) * 64;
    const u16* kl_base = klo_g + ((size_t)bt * 2048 + hw_base) * 64;
    // K fragment address for this wave (row m = hw0 + msub*16 + l15)
    const size_t k_off = (size_t)(msub * 16 + l15) * 64 + quad * 8;
    // V fragment base for this wave's c-quarter: c = w*64 + cs*16 + l15
    const u16* v_frag_base = vb_g + (size_t)bt * CVD * 2048 + hw_base
                           + (size_t)(w * 64 + l15) * 2048 + quad * 8;

    f32x4 O[4][4];                      // [nsub][cs]
    #pragma unroll
    for (int i = 0; i < 4; ++i)
        #pragma unroll
        for (int j = 0; j < 4; ++j)
            O[i][j] = (f32x4){0.f, 0.f, 0.f, 0.f};
    float Lloc[2] = {0.f, 0.f};

    // ---- double-buffered fragment registers (parity-indexed, unroll 2) ----
    bf16x8 kh[2][2], kl[2][2], vv[2][4];
    #pragma unroll
    for (int ks = 0; ks < 2; ++ks) {
        kh[0][ks] = *(const bf16x8*)&kh_base[k_off + ks * 32];
        kl[0][ks] = *(const bf16x8*)&kl_base[k_off + ks * 32];
    }
    #pragma unroll
    for (int cs = 0; cs < 4; ++cs)
        vv[0][cs] = *(const bf16x8*)&v_frag_base[(size_t)(cs * 16) * 2048];

    #pragma unroll 2
    for (int it = 0; it < NIT; ++it) {
        const int p = it & 1;
        u16* Ps = Ps2[p];

        // ---- prefetch it+1 (issued first: covered by QK+exp before SYNC) ----
        if (it + 1 < NIT) {
            const size_t row64 = (size_t)(it + 1) * TM * 64;
            const int hw1 = (it + 1) * TM;
            #pragma unroll
            for (int ks = 0; ks < 2; ++ks) {
                kh[p ^ 1][ks] = *(const bf16x8*)&kh_base[row64 + k_off + ks * 32];
                kl[p ^ 1][ks] = *(const bf16x8*)&kl_base[row64 + k_off + ks * 32];
            }
            #pragma unroll
            for (int cs = 0; cs < 4; ++cs)
                vv[p ^ 1][cs] = *(const bf16x8*)&v_frag_base[(size_t)(cs * 16) * 2048 + hw1];
        }

        // ---- QK: S[msub*16..+16][nsubpair*32..+32], 4 independent chains ----
        f32x4 acch[2], accl[2];
        acch[0] = (f32x4){0.f, 0.f, 0.f, 0.f};
        acch[1] = (f32x4){0.f, 0.f, 0.f, 0.f};
        accl[0] = (f32x4){0.f, 0.f, 0.f, 0.f};
        accl[1] = (f32x4){0.f, 0.f, 0.f, 0.f};
        #pragma unroll
        for (int ks = 0; ks < 2; ++ks) {
            #pragma unroll
            for (int nsi = 0; nsi < 2; ++nsi) {
                acch[nsi] = MFMA(kh[p][ks], qh[nsi][ks], acch[nsi]);
                accl[nsi] = MFMA(kh[p][ks], ql[nsi][ks], accl[nsi]);
                accl[nsi] = MFMA(kl[p][ks], qh[nsi][ks], accl[nsi]);
            }
        }
        // ---- P = exp2(S') (Q pre-scaled by log2 e) -> Ps[n][m]; accumulate L ----
        #pragma unroll
        for (int nsi = 0; nsi < 2; ++nsi) {
            int n = (nsubpair * 2 + nsi) * 16 + l15;
            float p0 = exp2f(acch[nsi][0] + accl[nsi][0]);
            float p1 = exp2f(acch[nsi][1] + accl[nsi][1]);
            float p2 = exp2f(acch[nsi][2] + accl[nsi][2]);
            float p3 = exp2f(acch[nsi][3] + accl[nsi][3]);
            Lloc[nsi] += (p0 + p1) + (p2 + p3);
            U16x4 pk = {f2bf(p0), f2bf(p1), f2bf(p2), f2bf(p3)};
            *(U16x4*)&Ps[n * 40 + msub * 16 + quad * 4] = pk;
        }
        __syncthreads();   // the ONE barrier: Ps(p) visible to all waves

        // ---- PV: wave owns O[all 64 n][c-quarter w*64..+64] ----
        bf16x8 a2[4];
        #pragma unroll
        for (int nsub = 0; nsub < 4; ++nsub)
            a2[nsub] = *(const bf16x8*)&Ps[(nsub * 16 + l15) * 40 + quad * 8];
        #pragma unroll
        for (int cs = 0; cs < 4; ++cs)
            #pragma unroll
            for (int nsub = 0; nsub < 4; ++nsub)
                O[nsub][cs] = MFMA(a2[nsub], vv[p][cs], O[nsub][cs]);
        // no barrier here: next iter writes the other Ps buffer; WAR on Ps(p)
        // (rewrite at it+2) is separated by SYNC(it+1) whose lgkmcnt drain
        // guarantees these reads completed.
    }

    // ---- L partials: fold quads via shuffle, plain store (disjoint slices) ----
    #pragma unroll
    for (int nsi = 0; nsi < 2; ++nsi) {
        float v = Lloc[nsi];
        v += __shfl_xor(v, 16);
        v += __shfl_xor(v, 32);
        if (quad == nsi) {
            int nsub = nsubpair * 2 + nsi;
            Lp[(((size_t)mchunk * 2 + msub) * BATCH + b) * NQ + ntile * TQ + nsub * 16 + l15] = v;
        }
    }

    // ---- U partials: plain coalesced fp32 stores, layout [ms][b][n][c] ----
    float* ubase = Up + (((size_t)mchunk * BATCH + b) * NQ + ntile * TQ) * CVD + w * 64;
    #pragma unroll
    for (int nsub = 0; nsub < 4; ++nsub) {
        #pragma unroll
        for (int cs = 0; cs < 4; ++cs) {
            #pragma unroll
            for (int r = 0; r < 4; ++r) {
                int n_local = nsub * 16 + quad * 4 + r;
                ubase[(size_t)n_local * CVD + cs * 16 + l15] = O[nsub][cs][r];
            }
        }
    }
}

// ---------------------------------------------------------------------------
// reduce_div: out[b,256+c,n] = (sum_ms Up[ms][b][n][c]) / (sum_s Lp[s][b][n])
// Grid: 1024 = b(2) x nslab(128, 16 n each) x cquarter(4, 64 c each).
// ---------------------------------------------------------------------------
__global__ __launch_bounds__(256) void reduce_div(const float* __restrict__ Up,
                                                  const float* __restrict__ Lp,
                                                  float* __restrict__ out) {
    __shared__ float lds[16 * 65];
    const int tid = threadIdx.x;
    const int cq  = blockIdx.x & 3;
    const int n0  = ((blockIdx.x >> 2) & 127) * 16;
    const int b   = blockIdx.x >> 9;

    const int n_local = tid >> 4;          // 0..15
    const int c_loc   = (tid & 15) * 4;    // 0..60
    const int c       = cq * 64 + c_loc;

    float4 acc = {0.f, 0.f, 0.f, 0.f};
    for (int ms = 0; ms < MSPLIT; ++ms) {
        float4 v = *(const float4*)(Up + (((size_t)ms * BATCH + b) * NQ + n0 + n_local) * CVD + c);
        acc.x += v.x; acc.y += v.y; acc.z += v.z; acc.w += v.w;
    }

    float Lsum = 0.f;
    #pragma unroll
    for (int s = 0; s < MSPLIT * 2; ++s)
        Lsum += Lp[((size_t)s * BATCH + b) * NQ + n0 + n_local];
    const float inv = 1.0f / Lsum;

    lds[n_local * 65 + c_loc + 0] = acc.x * inv;
    lds[n_local * 65 + c_loc + 1] = acc.y * inv;
    lds[n_local * 65 + c_loc + 2] = acc.z * inv;
    lds[n_local * 65 + c_loc + 3] = acc.w * inv;
    __syncthreads();

    // transpose write: out[b][256+cq*64+c_out][n0 + nq .. +4)
    const int c_out = tid >> 2;            // 0..63
    const int nq    = (tid & 3) * 4;       // 0..12
    float4 v;
    v.x = lds[(nq + 0) * 65 + c_out];
    v.y = lds[(nq + 1) * 65 + c_out];
    v.z = lds[(nq + 2) * 65 + c_out];
    v.w = lds[(nq + 3) * 65 + c_out];
    *(float4*)(out + ((size_t)(b * 512 + 256 + cq * 64 + c_out)) * NQ + n0 + nq) = v;
}

extern "C" void kernel_launch(void* const* d_in, const int* in_sizes, int n_in,
                              void* d_out, int out_size, void* d_ws, size_t ws_size,
                              hipStream_t stream) {
    const float* qv = (const float*)d_in[0];   // query_value       [2,256,64,128]
    const float* mk = (const float*)d_in[1];   // memory_keys_low   [2,4,64,32,64]
    const float* mv = (const float*)d_in[2];   // memory_values_low [2,4,256,32,64]
    const float* qk = (const float*)d_in[3];   // query_key_low     [2,64,32,64]
    float* out = (float*)d_out;                // [2,512,32,64] fp32

    u16*   vb  = (u16*)((char*)d_ws + WS_VB);
    u16*   khi = (u16*)((char*)d_ws + WS_KHI);
    u16*   klo = (u16*)((char*)d_ws + WS_KLO);
    u16*   qhi = (u16*)((char*)d_ws + WS_QHI);
    u16*   qlo = (u16*)((char*)d_ws + WS_QLO);
    float* Lp  = (float*)((char*)d_ws + WS_LP);
    float* Up  = (float*)((char*)d_ws + WS_UP);

    prep_fused<<<6464, 256, 0, stream>>>(qv, mk, qk, mv, out, vb, khi, klo, qhi, qlo);
    flash_attn<<<512, 256, 0, stream>>>(khi, klo, vb, qhi, qlo, Up, Lp);
    reduce_div<<<1024, 256, 0, stream>>>(Up, Lp, out);
}

// Round 12
// 131.156 us; speedup vs baseline: 1.2668x; 1.2154x over previous
//
#include <hip/hip_runtime.h>
#include <cstdint>

// Problem constants
#define BATCH 2
#define TT    4
#define CKD   64      // key channels
#define CVD   256     // value channels
#define NQ    2048    // H*W (queries per batch)
#define MM    8192    // T*H*W (memory positions per batch)
#define TQ    64      // queries per block
#define TM    32      // memory rows per inner iteration
#define MSPLIT 8
#define MCHUNK (MM / MSPLIT)   // 1024 = half a T-slice
#define NIT    (MCHUNK / TM)   // 32

typedef unsigned short u16;
typedef __bf16 bf16x8 __attribute__((ext_vector_type(8)));
typedef float  f32x4  __attribute__((ext_vector_type(4)));

struct __attribute__((aligned(8)))  U16x4 { u16 x, y, z, w; };
struct __attribute__((aligned(16))) U16x8 { u16 v[8]; };

__device__ __forceinline__ u16 f2bf(float x) {
    uint32_t u = __float_as_uint(x);
    uint32_t r = (u + 0x7FFFu + ((u >> 16) & 1u)) >> 16;   // RNE
    return (u16)r;
}
__device__ __forceinline__ float bf2f(u16 h) {
    return __uint_as_float(((uint32_t)h) << 16);
}

#define MFMA(a, b, c) __builtin_amdgcn_mfma_f32_16x16x32_bf16((a), (b), (c), 0, 0, 0)

// Workspace layout (bytes) — Up now bf16: ws usage 47.4 -> 30.7 MB
#define WS_VB   0u           // 8 MB   bf16 V   [bt][c][m]
#define WS_KHI  8388608u     // 2 MB   bf16 Khi [bt][m][c]
#define WS_KLO  10485760u    // 2 MB   bf16 Klo [bt][m][c]
#define WS_QHI  12582912u    // 512 KB bf16 Qhi [b][n][c]
#define WS_QLO  13107200u    // 512 KB
#define WS_LP   13631488u    // 256 KB fp32 Lp[ms][msub][b][n] (plain stores)
#define WS_UP   13893632u    // 16.8 MB bf16 Up[ms][b][n][c]  (coalesced stores)

// ---------------------------------------------------------------------------
// prep_fused (identical to the R8 version that produced flash=48us):
//   [0,4096)    pool_qv: 2x2 avg-pool query_value -> out channels [0,256)
//   [4096,6144) prep_v : fp32 V -> bf16, same [bt][c][m] layout
//   [6144,6400) prep_kq(mk): coalesced read + LDS transpose -> bf16 hi/lo [m][c]
//   [6400,6464) prep_kq(qk): same for query_key_low
// ---------------------------------------------------------------------------
__global__ __launch_bounds__(256)
void prep_fused(const float* __restrict__ qv, const float* __restrict__ mk,
                const float* __restrict__ qk, const float* __restrict__ mv,
                float* __restrict__ out, u16* __restrict__ vb,
                u16* __restrict__ khi, u16* __restrict__ klo,
                u16* __restrict__ qhi, u16* __restrict__ qlo) {
    __shared__ float tile[64 * 65];   // kq branch only (block-uniform branches)
    const int bid = blockIdx.x;
    const int tid = threadIdx.x;

    if (bid < 4096) {
        // ---- pool_qv ----
        int idx = bid * 256 + tid;
        int n  = idx & 2047;
        int bc = idx >> 11;
        int x = n & 63, y = n >> 6;
        const float* ib = qv + (size_t)bc * (64 * 128) + (2 * y) * 128 + 2 * x;
        float2 r0 = *(const float2*)ib;
        float2 r1 = *(const float2*)(ib + 128);
        int b = bc >> 8, c = bc & 255;
        out[((size_t)(b * 512 + c)) * NQ + n] = 0.25f * (r0.x + r0.y + r1.x + r1.y);
    } else if (bid < 6144) {
        // ---- prep_v ----
        int idx = (bid - 4096) * 256 + tid;        // 0 .. 524287
        const float4* s = (const float4*)mv + (size_t)idx * 2;
        float4 a = s[0], b = s[1];
        U16x8 o;
        o.v[0] = f2bf(a.x); o.v[1] = f2bf(a.y); o.v[2] = f2bf(a.z); o.v[3] = f2bf(a.w);
        o.v[4] = f2bf(b.x); o.v[5] = f2bf(b.y); o.v[6] = f2bf(b.z); o.v[7] = f2bf(b.w);
        *(U16x8*)(vb + (size_t)idx * 8) = o;
    } else {
        // ---- prep_kq: per block one 64c x 64m tile, transposed via LDS ----
        const float* src;
        u16 *dhi, *dlo;
        int blk;
        if (bid < 6400) { src = mk; dhi = khi; dlo = klo; blk = bid - 6144; }
        else            { src = qk; dhi = qhi; dlo = qlo; blk = bid - 6400; }
        const int g  = blk >> 5;           // mk: 0..7, qk: 0..1
        const int mg = blk & 31;           // 64-m tile index
        const float* s = src + (size_t)g * 64 * 2048 + mg * 64;

        // coalesced read: c = tid>>2, q = tid&3; 4 float4 per thread
        const int c = tid >> 2;
        const int q = tid & 3;
        #pragma unroll
        for (int i = 0; i < 4; ++i) {
            float4 v = *(const float4*)(s + (size_t)c * 2048 + q * 16 + i * 4);
            int m = q * 16 + i * 4;
            tile[(m + 0) * 65 + c] = v.x;
            tile[(m + 1) * 65 + c] = v.y;
            tile[(m + 2) * 65 + c] = v.z;
            tile[(m + 3) * 65 + c] = v.w;
        }
        __syncthreads();

        // coalesced write: mo = tid>>2, cb = (tid&3)*16; hi/lo split here
        const int mo = tid >> 2;
        const int cb = (tid & 3) * 16;
        U16x8 h0, h1, l0, l1;
        #pragma unroll
        for (int j = 0; j < 8; ++j) {
            float v = tile[mo * 65 + cb + j];
            u16 h = f2bf(v);
            h0.v[j] = h; l0.v[j] = f2bf(v - bf2f(h));
            float v2 = tile[mo * 65 + cb + 8 + j];
            u16 h2 = f2bf(v2);
            h1.v[j] = h2; l1.v[j] = f2bf(v2 - bf2f(h2));
        }
        size_t o = ((size_t)g * 2048 + mg * 64 + mo) * 64 + cb;
        *(U16x8*)(dhi + o) = h0; *(U16x8*)(dhi + o + 8) = h1;
        *(U16x8*)(dlo + o) = l0; *(U16x8*)(dlo + o + 8) = l1;
    }
}

// ---------------------------------------------------------------------------
// flash_attn (R12): EXACT R8 main loop (the proven local optimum, 48us):
// K staged in LDS (dbuf), V fragment-loaded straight from global [c][m]
// (layout == B-operand layout; L2 absorbs re-reads), Ps dbuf, 2 barriers.
//   stage K(p) | sync1 | QK -> exp -> Ps(p) | sync2 | prefetch | PV
// ONLY change vs R8: bf16 Up epilogue — O fragments round-trip through LDS
// (wave-disjoint 8KB regions) and exit as 128B-contiguous dwordx4 stores.
// WRITE halves (33 -> 17 MB); reduce_div reads halve; ws usage -16 MB.
// Grid: 512 = b(2) x ntile(32) x mchunk(8). Block 256 = 4 waves.
// ---------------------------------------------------------------------------
__global__ __launch_bounds__(256, 2)
void flash_attn(const u16* __restrict__ khi_g, const u16* __restrict__ klo_g,
                const u16* __restrict__ vb_g, const u16* __restrict__ qhi_g,
                const u16* __restrict__ qlo_g, u16* __restrict__ Up,
                float* __restrict__ Lp) {
    // Main loop: 2 buffers x 7168 u16 (Khi[32][72] | Klo[32][72] | Ps[64][40]).
    // Epilogue: reused as 4 x 4096 u16 wave-disjoint staging (32 KB total).
    __shared__ __align__(16) u16 smem[16384];

    const int tid    = threadIdx.x;
    const int bx     = blockIdx.x;
    const int mchunk = bx & 7;
    const int ntile  = (bx >> 3) & 31;
    const int b      = bx >> 8;

    const int lane = tid & 63;
    const int w    = tid >> 6;
    const int quad = lane >> 4;
    const int l15  = lane & 15;

    const int bt      = b * TT + (mchunk >> 1);
    const int hw_base = (mchunk & 1) * MCHUNK;

    // ---- Q fragments straight from pre-transposed global [b][n][c] ----
    bf16x8 qh[2][2], ql[2][2];          // [nsi][kstep]
    {
        const int nbase = ntile * TQ + (w >> 1) * 32;
        #pragma unroll
        for (int nsi = 0; nsi < 2; ++nsi) {
            size_t o = ((size_t)(b * NQ + nbase + nsi * 16 + l15)) * 64 + quad * 8;
            qh[nsi][0] = *(const bf16x8*)&qhi_g[o];
            qh[nsi][1] = *(const bf16x8*)&qhi_g[o + 32];
            ql[nsi][0] = *(const bf16x8*)&qlo_g[o];
            ql[nsi][1] = *(const bf16x8*)&qlo_g[o + 32];
        }
    }

    const u16* kh_base = khi_g + ((size_t)bt * 2048 + hw_base) * 64;
    const u16* kl_base = klo_g + ((size_t)bt * 2048 + hw_base) * 64;
    // V fragment base for this wave's c-quarter: c = w*64 + cs*16 + l15
    const u16* v_frag_base = vb_g + (size_t)bt * CVD * 2048 + hw_base
                           + (size_t)(w * 64 + l15) * 2048 + quad * 8;

    f32x4 O[4][4];                      // [nsub][cs]
    #pragma unroll
    for (int i = 0; i < 4; ++i)
        #pragma unroll
        for (int j = 0; j < 4; ++j)
            O[i][j] = (f32x4){0.f, 0.f, 0.f, 0.f};
    float Lloc[2] = {0.f, 0.f};

    const int msub     = w & 1;         // QK role
    const int nsubpair = w >> 1;        // QK role

    // K staging lane map
    const int km = tid >> 3;            // 0..31
    const int kc = (tid & 7) * 8;       // 0..56

    // ---- prologue: prefetch iter 0 (K to staging regs, V frags to regs) ----
    bf16x8 kh_r = *(const bf16x8*)&kh_base[(size_t)km * 64 + kc];
    bf16x8 kl_r = *(const bf16x8*)&kl_base[(size_t)km * 64 + kc];
    bf16x8 v_cur[4], v_next[4];
    #pragma unroll
    for (int cs = 0; cs < 4; ++cs)
        v_cur[cs] = *(const bf16x8*)&v_frag_base[(size_t)(cs * 16) * 2048];

    #pragma unroll 2
    for (int it = 0; it < NIT; ++it) {
        u16* Khi = smem + (it & 1) * 7168;
        u16* Klo = Khi + 2304;
        u16* Ps  = Khi + 4608;

        // ---- stage K tile into this iteration's buffer ----
        *(bf16x8*)&Khi[km * 72 + kc] = kh_r;
        *(bf16x8*)&Klo[km * 72 + kc] = kl_r;
        __syncthreads();   // sync1: K staging visible

        // ---- QK: S[msub*16..+16][nsubpair*32..+32], 3-term hi/lo split ----
        f32x4 acc[2];
        acc[0] = (f32x4){0.f, 0.f, 0.f, 0.f};
        acc[1] = (f32x4){0.f, 0.f, 0.f, 0.f};
        #pragma unroll
        for (int ks = 0; ks < 2; ++ks) {
            bf16x8 ah = *(const bf16x8*)&Khi[(msub * 16 + l15) * 72 + ks * 32 + quad * 8];
            bf16x8 al = *(const bf16x8*)&Klo[(msub * 16 + l15) * 72 + ks * 32 + quad * 8];
            #pragma unroll
            for (int nsi = 0; nsi < 2; ++nsi) {
                acc[nsi] = MFMA(ah, qh[nsi][ks], acc[nsi]);
                acc[nsi] = MFMA(ah, ql[nsi][ks], acc[nsi]);
                acc[nsi] = MFMA(al, qh[nsi][ks], acc[nsi]);
            }
        }
        // ---- P = exp(S) -> Ps[n][m] (A-operand layout); accumulate L ----
        #pragma unroll
        for (int nsi = 0; nsi < 2; ++nsi) {
            int n = (nsubpair * 2 + nsi) * 16 + l15;
            float p0 = __expf(acc[nsi][0]);
            float p1 = __expf(acc[nsi][1]);
            float p2 = __expf(acc[nsi][2]);
            float p3 = __expf(acc[nsi][3]);
            Lloc[nsi] += (p0 + p1) + (p2 + p3);
            U16x4 pk = {f2bf(p0), f2bf(p1), f2bf(p2), f2bf(p3)};
            *(U16x4*)&Ps[n * 40 + msub * 16 + quad * 4] = pk;
        }
        __syncthreads();   // sync2: Ps visible; K reads done

        // ---- prefetch it+1 (drains at sync1(it+1), covered by PV span) ----
        if (it + 1 < NIT) {
            const int hw1 = (it + 1) * TM;
            kh_r = *(const bf16x8*)&kh_base[(size_t)(hw1 + km) * 64 + kc];
            kl_r = *(const bf16x8*)&kl_base[(size_t)(hw1 + km) * 64 + kc];
            #pragma unroll
            for (int cs = 0; cs < 4; ++cs)
                v_next[cs] = *(const bf16x8*)&v_frag_base[(size_t)(cs * 16) * 2048 + hw1];
        }

        // ---- PV: wave owns O[all 64 n][c-quarter w*64..+64] ----
        bf16x8 a2[4];
        #pragma unroll
        for (int nsub = 0; nsub < 4; ++nsub)
            a2[nsub] = *(const bf16x8*)&Ps[(nsub * 16 + l15) * 40 + quad * 8];
        #pragma unroll
        for (int cs = 0; cs < 4; ++cs)
            #pragma unroll
            for (int nsub = 0; nsub < 4; ++nsub)
                O[nsub][cs] = MFMA(a2[nsub], v_cur[cs], O[nsub][cs]);

        // ---- rotate V prefetch ----
        #pragma unroll
        for (int cs = 0; cs < 4; ++cs)
            v_cur[cs] = v_next[cs];
        // no barrier: next staging writes the other K/Ps buffer
    }

    // ---- L partials: fold quads via shuffle, plain store (disjoint slices) ----
    #pragma unroll
    for (int nsi = 0; nsi < 2; ++nsi) {
        float v = Lloc[nsi];
        v += __shfl_xor(v, 16);
        v += __shfl_xor(v, 32);
        if (quad == nsi) {
            int nsub = nsubpair * 2 + nsi;
            Lp[(((size_t)mchunk * 2 + msub) * BATCH + b) * NQ + ntile * TQ + nsub * 16 + l15] = v;
        }
    }

    // ---- U partials: bf16, coalesced via LDS transpose ----
    // Wave-disjoint 8KB staging: Uw[64 n][64 c] u16. One barrier protects the
    // final iteration's Ps readers before smem is repurposed.
    __syncthreads();
    u16* Uw = smem + w * 4096;
    #pragma unroll
    for (int nsub = 0; nsub < 4; ++nsub) {
        #pragma unroll
        for (int cs = 0; cs < 4; ++cs) {
            #pragma unroll
            for (int r = 0; r < 4; ++r) {
                int n_local = nsub * 16 + quad * 4 + r;
                Uw[n_local * 64 + cs * 16 + l15] = f2bf(O[nsub][cs][r]);
            }
        }
    }
    // read back coalesced: 8 insts x (64 lanes x 16B); each 16B = one n-row's
    // 8-c chunk; global rows are 128B-contiguous per wave at 512B stride.
    u16* ubase = Up + (((size_t)mchunk * BATCH + b) * NQ + ntile * TQ) * CVD + w * 64;
    #pragma unroll
    for (int i = 0; i < 8; ++i) {
        int idx = i * 64 + lane;            // 0..511
        U16x8 val = *(const U16x8*)&Uw[idx * 8];
        int n  = idx >> 3;
        int c8 = (idx & 7) * 8;
        *(U16x8*)&ubase[(size_t)n * CVD + c8] = val;
    }
}

// ---------------------------------------------------------------------------
// reduce_div: out[b,256+c,n] = (sum_ms Up_bf16[ms][b][n][c]) / (sum_s Lp[s][b][n])
// Grid: 1024 = b(2) x nslab(128, 16 n each) x cquarter(4, 64 c each).
// ---------------------------------------------------------------------------
__global__ __launch_bounds__(256) void reduce_div(const u16* __restrict__ Up,
                                                  const float* __restrict__ Lp,
                                                  float* __restrict__ out) {
    __shared__ float lds[16 * 65];
    const int tid = threadIdx.x;
    const int cq  = blockIdx.x & 3;
    const int n0  = ((blockIdx.x >> 2) & 127) * 16;
    const int b   = blockIdx.x >> 9;

    const int n_local = tid >> 4;          // 0..15
    const int c_loc   = (tid & 15) * 4;    // 0..60
    const int c       = cq * 64 + c_loc;

    float a0 = 0.f, a1 = 0.f, a2 = 0.f, a3 = 0.f;
    for (int ms = 0; ms < MSPLIT; ++ms) {
        U16x4 v = *(const U16x4*)(Up + (((size_t)ms * BATCH + b) * NQ + n0 + n_local) * CVD + c);
        a0 += bf2f(v.x); a1 += bf2f(v.y); a2 += bf2f(v.z); a3 += bf2f(v.w);
    }

    float Lsum = 0.f;
    #pragma unroll
    for (int s = 0; s < MSPLIT * 2; ++s)
        Lsum += Lp[((size_t)s * BATCH + b) * NQ + n0 + n_local];
    const float inv = 1.0f / Lsum;

    lds[n_local * 65 + c_loc + 0] = a0 * inv;
    lds[n_local * 65 + c_loc + 1] = a1 * inv;
    lds[n_local * 65 + c_loc + 2] = a2 * inv;
    lds[n_local * 65 + c_loc + 3] = a3 * inv;
    __syncthreads();

    // transpose write: out[b][256+cq*64+c_out][n0 + nq .. +4)
    const int c_out = tid >> 2;            // 0..63
    const int nq    = (tid & 3) * 4;       // 0..12
    float4 v;
    v.x = lds[(nq + 0) * 65 + c_out];
    v.y = lds[(nq + 1) * 65 + c_out];
    v.z = lds[(nq + 2) * 65 + c_out];
    v.w = lds[(nq + 3) * 65 + c_out];
    *(float4*)(out + ((size_t)(b * 512 + 256 + cq * 64 + c_out)) * NQ + n0 + nq) = v;
}

extern "C" void kernel_launch(void* const* d_in, const int* in_sizes, int n_in,
                              void* d_out, int out_size, void* d_ws, size_t ws_size,
                              hipStream_t stream) {
    const float* qv = (const float*)d_in[0];   // query_value       [2,256,64,128]
    const float* mk = (const float*)d_in[1];   // memory_keys_low   [2,4,64,32,64]
    const float* mv = (const float*)d_in[2];   // memory_values_low [2,4,256,32,64]
    const float* qk = (const float*)d_in[3];   // query_key_low     [2,64,32,64]
    float* out = (float*)d_out;                // [2,512,32,64] fp32

    u16*   vb  = (u16*)((char*)d_ws + WS_VB);
    u16*   khi = (u16*)((char*)d_ws + WS_KHI);
    u16*   klo = (u16*)((char*)d_ws + WS_KLO);
    u16*   qhi = (u16*)((char*)d_ws + WS_QHI);
    u16*   qlo = (u16*)((char*)d_ws + WS_QLO);
    float* Lp  = (float*)((char*)d_ws + WS_LP);
    u16*   Up  = (u16*)((char*)d_ws + WS_UP);

    prep_fused<<<6464, 256, 0, stream>>>(qv, mk, qk, mv, out, vb, khi, klo, qhi, qlo);
    flash_attn<<<512, 256, 0, stream>>>(khi, klo, vb, qhi, qlo, Up, Lp);
    reduce_div<<<1024, 256, 0, stream>>>(Up, Lp, out);
}